// Round 1
// baseline (38439.944 us; speedup 1.0000x reference)
//
#include <hip/hip_runtime.h>

typedef _Float16 f16;
typedef f16 f16x2 __attribute__((ext_vector_type(2)));
typedef f16 f16x4 __attribute__((ext_vector_type(4)));
typedef f16 f16x8 __attribute__((ext_vector_type(8)));
typedef float f32x4 __attribute__((ext_vector_type(4)));

#define R 4096
#define IN_DIM 256
#define T_STEPS 4096
#define NBLK 256
#define TPB 1024
#define WPB 16   // waves per block = rows per block

#ifdef __has_builtin
#if __has_builtin(__builtin_amdgcn_fdot2)
#define HAVE_FDOT2 1
#endif
#endif
#ifndef HAVE_FDOT2
#define HAVE_FDOT2 0
#endif

// ---- W f32 -> fp16 conversion (re-run every call; deterministic) ----
__global__ void wconv_kernel(const float* __restrict__ W, f16* __restrict__ Wh) {
    size_t i = ((size_t)blockIdx.x * 256 + threadIdx.x) * 4;
    f32x4 v = *(const f32x4*)(W + i);
    f16x4 o = { (f16)v.x, (f16)v.y, (f16)v.z, (f16)v.w };
    *(f16x4*)(Wh + i) = o;
}

// ---- persistent scan kernel: 256 blocks, 16 waves each, 1 row per wave ----
template <typename WT>
__global__ __launch_bounds__(TPB) void esn_kernel(
    const float* __restrict__ x,      // [T][256]
    const float* __restrict__ Win,    // [R][256]
    const WT*    __restrict__ W,      // [R][R]
    float* h0, float* h1,             // double-buffered state (ws, zeroed)
    unsigned int* counter,            // monotonic barrier counter (ws, zeroed)
    const float* __restrict__ Wout,   // [256][R]
    const float* __restrict__ bias,   // [256]
    float* __restrict__ out)          // [256]
{
    __shared__ WT    h_lds[R];        // staged h (fp16: 8KB, f32: 16KB)
    __shared__ float x_lds[IN_DIM];   // staged x[t]
    __shared__ float red[WPB];

    const int tid  = threadIdx.x;
    const int b    = blockIdx.x;
    const int wave = tid >> 6;
    const int lane = tid & 63;
    const int row  = b * WPB + wave;
    const WT*    wrow   = W   + (size_t)row * R;
    const float* winrow = Win + (size_t)row * IN_DIM;

    constexpr int EP = 16 / (int)sizeof(WT);  // elems per 16B lane-load
    constexpr int CH = R / (64 * EP);         // chunks per row

    for (int t = 0; t < T_STEPS; ++t) {
        float* h_in  = (t & 1) ? h1 : h0;
        float* h_out = (t & 1) ? h0 : h1;

        // stage x[t] and h_in (agent-scope loads: bypass stale per-XCD L2)
        if (tid < IN_DIM) x_lds[tid] = x[(size_t)t * IN_DIM + tid];
#pragma unroll
        for (int k = 0; k < R / TPB; ++k) {
            int j = tid + k * TPB;
            float v = __hip_atomic_load(h_in + j, __ATOMIC_RELAXED,
                                        __HIP_MEMORY_SCOPE_AGENT);
            h_lds[j] = (WT)v;
        }
        __syncthreads();

        // dot(W[row,:], h) — lane handles EP contiguous elems per chunk
        float acc = 0.f;
#pragma unroll
        for (int c = 0; c < CH; ++c) {
            const int j0 = (c * 64 + lane) * EP;
            if constexpr (sizeof(WT) == 2) {
                f16x8 av = *(const f16x8*)(wrow + j0);
                f16x8 bv = *(const f16x8*)(h_lds + j0);
#if HAVE_FDOT2
#pragma unroll
                for (int k = 0; k < 4; ++k) {
                    f16x2 a2 = { av[2 * k], av[2 * k + 1] };
                    f16x2 b2 = { bv[2 * k], bv[2 * k + 1] };
                    acc = __builtin_amdgcn_fdot2(a2, b2, acc, false);
                }
#else
#pragma unroll
                for (int k = 0; k < 8; ++k)
                    acc = fmaf((float)av[k], (float)bv[k], acc);
#endif
            } else {
                f32x4 av = *(const f32x4*)(wrow + j0);
                f32x4 bv = *(const f32x4*)(h_lds + j0);
                acc = fmaf(av.x, bv.x, acc);
                acc = fmaf(av.y, bv.y, acc);
                acc = fmaf(av.z, bv.z, acc);
                acc = fmaf(av.w, bv.w, acc);
            }
        }
        // fused input projection: dot(Win[row,:], x[t,:])
        {
            const f32x4 wv = *(const f32x4*)(winrow + lane * 4);
            const f32x4 xv = *(const f32x4*)(&x_lds[lane * 4]);
            acc = fmaf(wv.x, xv.x, acc);
            acc = fmaf(wv.y, xv.y, acc);
            acc = fmaf(wv.z, xv.z, acc);
            acc = fmaf(wv.w, xv.w, acc);
        }
        // wave-64 butterfly reduce
#pragma unroll
        for (int off = 32; off > 0; off >>= 1)
            acc += __shfl_xor(acc, off, 64);

        if (lane == 0) {
            float hv = tanhf(acc);
            __hip_atomic_store(h_out + row, hv, __ATOMIC_RELAXED,
                               __HIP_MEMORY_SCOPE_AGENT);
        }
        __syncthreads();  // all waves' h stores issued+drained before signal

        // device-wide barrier: monotonic counter, no reset between steps
        if (tid == 0) {
            __hip_atomic_fetch_add(counter, 1u, __ATOMIC_RELEASE,
                                   __HIP_MEMORY_SCOPE_AGENT);
            const unsigned int target = (unsigned int)(t + 1) * NBLK;
            while (__hip_atomic_load(counter, __ATOMIC_ACQUIRE,
                                     __HIP_MEMORY_SCOPE_AGENT) < target) {
                __builtin_amdgcn_s_sleep(1);
            }
        }
        __syncthreads();
    }

    // out[b] = Wout[b,:] . h_final + bias[b]   (T even -> final h in h0)
    {
        float* hf = h0;
        const float* worow = Wout + (size_t)b * R;
        const int j0 = tid * 4;
        f32x4 wv = *(const f32x4*)(worow + j0);
        float a0 = __hip_atomic_load(hf + j0 + 0, __ATOMIC_RELAXED, __HIP_MEMORY_SCOPE_AGENT);
        float a1 = __hip_atomic_load(hf + j0 + 1, __ATOMIC_RELAXED, __HIP_MEMORY_SCOPE_AGENT);
        float a2 = __hip_atomic_load(hf + j0 + 2, __ATOMIC_RELAXED, __HIP_MEMORY_SCOPE_AGENT);
        float a3 = __hip_atomic_load(hf + j0 + 3, __ATOMIC_RELAXED, __HIP_MEMORY_SCOPE_AGENT);
        float acc = wv.x * a0 + wv.y * a1 + wv.z * a2 + wv.w * a3;
#pragma unroll
        for (int off = 32; off > 0; off >>= 1)
            acc += __shfl_xor(acc, off, 64);
        if (lane == 0) red[wave] = acc;
        __syncthreads();
        if (tid == 0) {
            float s = bias[b];
            for (int w = 0; w < WPB; ++w) s += red[w];
            out[b] = s;
        }
    }
}

extern "C" void kernel_launch(void* const* d_in, const int* in_sizes, int n_in,
                              void* d_out, int out_size, void* d_ws, size_t ws_size,
                              hipStream_t stream) {
    const float* x    = (const float*)d_in[0];
    const float* Win  = (const float*)d_in[1];
    const float* W    = (const float*)d_in[2];
    const float* Wout = (const float*)d_in[3];
    const float* bias = (const float*)d_in[4];
    float* out = (float*)d_out;

    char* ws = (char*)d_ws;
    unsigned int* counter = (unsigned int*)ws;           // @0
    float* h0 = (float*)(ws + 4096);                     // 16KB
    float* h1 = (float*)(ws + 4096 + R * 4);             // 16KB

    // zero counter + both h buffers every call (graph-capturable memset node)
    hipMemsetAsync(ws, 0, 65536, stream);

    const size_t need16 = 65536 + (size_t)R * R * sizeof(f16);
    if (ws_size >= need16) {
        f16* Wh = (f16*)(ws + 65536);
        wconv_kernel<<<(R * (size_t)R) / (256 * 4), 256, 0, stream>>>(W, Wh);
        esn_kernel<f16><<<NBLK, TPB, 0, stream>>>(x, Win, Wh, h0, h1, counter,
                                                  Wout, bias, out);
    } else {
        // workspace too small for fp16 copy: run straight from f32 W
        esn_kernel<float><<<NBLK, TPB, 0, stream>>>(x, Win, W, h0, h1, counter,
                                                    Wout, bias, out);
    }
}